// Round 2
// baseline (421.776 us; speedup 1.0000x reference)
//
#include <hip/hip_runtime.h>
#include <hip/hip_bf16.h>
#include <math.h>

#define NB 16
#define SS 64
#define HH 256
#define FAA 256

using short8 = __attribute__((ext_vector_type(8))) short;
using f32x4  = __attribute__((ext_vector_type(4))) float;

__device__ __forceinline__ float bf2f_u(unsigned int u) {
  union { unsigned int u; float f; } x; x.u = u << 16; return x.f;
}
__device__ __forceinline__ unsigned short f2bf(float f) {
  union { float f; unsigned int u; } x; x.f = f;
  unsigned int u = x.u;
  return (unsigned short)((u + 0x7FFFu + ((u >> 16) & 1u)) >> 16);  // RNE
}
__device__ __forceinline__ unsigned int pk2(float a, float b) {
  return (unsigned int)f2bf(a) | ((unsigned int)f2bf(b) << 16);
}

// ---------------------------------------------------------------------------
// Prolog: fp32 -> bf16 conversions of weights / reused activations.
// wcat layout: rows 0..255 = Ur[o][k], rows 256..511 = U[o-256][k], with the
// K dimension PERMUTED so that actual cols (g*32+l, g*32+16+l) sit at storage
// (g*32+2l, g*32+2l+1). gru_scan stores C in the same permuted order, letting
// the update write one u32 (cvt_pk) per col-pair. nmbf's middle K-section
// (cols 256..511 = C) gets the identical permutation so phase D is invariant.
// ---------------------------------------------------------------------------
__global__ void prolog_cvt(const float* __restrict__ z1w, const float* __restrict__ Ur,
                           const float* __restrict__ U, const float* __restrict__ nmw,
                           const float* __restrict__ pm, const float* __restrict__ qs,
                           unsigned short* __restrict__ z1wbf, unsigned short* __restrict__ wcatbf,
                           unsigned short* __restrict__ nmbf, unsigned short* __restrict__ pmbf,
                           unsigned short* __restrict__ qbf) {
  int idx = blockIdx.x * 256 + threadIdx.x;
  if (idx < 262144) { z1wbf[idx] = f2bf(z1w[idx]); return; }
  idx -= 262144;
  if (idx < 131072) {
    int o = idx >> 8, s = idx & 255;
    int t = s & 31;
    int cc = (s & ~31) + (t >> 1) + ((t & 1) << 4);  // storage s -> actual col
    wcatbf[idx] = f2bf(o < 256 ? Ur[o * 256 + cc] : U[(o - 256) * 256 + cc]);
    return;
  }
  idx -= 131072;
  if (idx < 196608) {
    int o = idx / 768, k = idx - o * 768;
    int kk = k;
    if (k >= 256 && k < 512) {
      int s = k - 256, t = s & 31;
      kk = 256 + (s & ~31) + (t >> 1) + ((t & 1) << 4);
    }
    nmbf[idx] = f2bf(nmw[o * 768 + kk]);
    return;
  }
  idx -= 196608;
  if (idx < 262144) { pmbf[idx] = f2bf(pm[idx]); return; }
  idx -= 262144;
  if (idx < 262144) { qbf[idx] = f2bf(qs[idx]); return; }
}

// ---------------------------------------------------------------------------
// Phase B: FWr[b,h] = facts[b]·Wr[h] + Wr_b[h] + Ur_b[h];  FW[b,h] = facts[b]·W[h] + W_b[h]
// ---------------------------------------------------------------------------
__global__ __launch_bounds__(256) void fact_proj(
    const float* __restrict__ facts, const float* __restrict__ Wr, const float* __restrict__ Wrb,
    const float* __restrict__ Urb, const float* __restrict__ Ww, const float* __restrict__ Wb,
    float* __restrict__ FWr, float* __restrict__ FW) {
  __shared__ float fl[4][HH];
  const int b0 = blockIdx.x * 4;
  const int tid = threadIdx.x;
#pragma unroll
  for (int r = 0; r < 4; ++r) fl[r][tid] = facts[(b0 + r) * HH + tid];
  __syncthreads();
  float ar[4] = {0.f, 0.f, 0.f, 0.f}, aw[4] = {0.f, 0.f, 0.f, 0.f};
  const float4* wr = (const float4*)(Wr + tid * HH);
  const float4* ww = (const float4*)(Ww + tid * HH);
  for (int d4 = 0; d4 < 64; ++d4) {
    float4 a = wr[d4], b = ww[d4];
#pragma unroll
    for (int r = 0; r < 4; ++r) {
      float4 f = *(const float4*)&fl[r][d4 * 4];  // LDS broadcast
      ar[r] += a.x * f.x + a.y * f.y + a.z * f.z + a.w * f.w;
      aw[r] += b.x * f.x + b.y * f.y + b.z * f.z + b.w * f.w;
    }
  }
  const float br = Wrb[tid] + Urb[tid], bw = Wb[tid];
#pragma unroll
  for (int r = 0; r < 4; ++r) {
    FWr[(b0 + r) * HH + tid] = ar[r] + br;
    FW[(b0 + r) * HH + tid] = aw[r] + bw;
  }
}

// ---------------------------------------------------------------------------
// Phase A: gate GEMM. Block = (n, 2 i's) -> 128 rows (2i x 64j) x 256 k, K=1024.
// ---------------------------------------------------------------------------
__global__ __launch_bounds__(512, 2) void gate_gemm(
    const float* __restrict__ facts, const float* __restrict__ prevM,
    const float* __restrict__ questions, const unsigned short* __restrict__ z1wbf,
    const float* __restrict__ z1b, const float* __restrict__ z2w,
    const float* __restrict__ z2b, float* __restrict__ G) {
  __shared__ unsigned short A[128][136];  // stride 136 (68 words, 4 mod 32 -> 2-way max)
  __shared__ float Gpart[128][4];
  const int bi = blockIdx.x;
  const int n = bi >> 5, i0 = (bi & 31) * 2;
  const int tid = threadIdx.x;
  const int w = tid >> 6, l = tid & 63;
  const int rg = w >> 2, cg = w & 3;        // rowgroup (i-local), colgroup
  const int l15 = l & 15, q = l >> 4;
  const int hh2 = (tid & 15) * 2, jb = tid >> 4;  // builder mapping

  const float* fn = facts + n * SS * HH;
  const float* qn = questions + (n * SS + i0) * HH;
  const float* mn = prevM + (n * SS + i0) * HH;

  const f32x4 zero4 = {0.f, 0.f, 0.f, 0.f};
  f32x4 acc[4][4];
#pragma unroll
  for (int a = 0; a < 4; ++a)
#pragma unroll
    for (int b = 0; b < 4; ++b) acc[a][b] = zero4;

  float2 fv0, fv1, qv0, qv1, mv0, mv1;
  auto prefetch = [&](int hc) {
    const int h = hc * 32 + hh2;
    fv0 = *(const float2*)(fn + jb * HH + h);
    fv1 = *(const float2*)(fn + (jb + 32) * HH + h);
    qv0 = *(const float2*)(qn + h);
    qv1 = *(const float2*)(qn + HH + h);
    mv0 = *(const float2*)(mn + h);
    mv1 = *(const float2*)(mn + HH + h);
  };
  prefetch(0);

  for (int hc = 0; hc < 8; ++hc) {
    short8 Bf[4][4];
    const unsigned short* bb = z1wbf + (cg * 64 + l15) * 1024 + hc * 32 + q * 8;
#pragma unroll
    for (int s = 0; s < 4; ++s)
#pragma unroll
      for (int nf = 0; nf < 4; ++nf)
        Bf[s][nf] = *(const short8*)(bb + (nf * 16) * 1024 + s * 256);

    {
      float2 fl2[2] = {fv0, fv1}, ql2[2] = {qv0, qv1}, ml2[2] = {mv0, mv1};
#pragma unroll
      for (int pl = 0; pl < 2; ++pl) {
        const int j = jb + pl * 32;
#pragma unroll
        for (int il = 0; il < 2; ++il) {
          const int row = il * 64 + j;
          const float fx = fl2[pl].x, fy = fl2[pl].y;
          const float qx = ql2[il].x, qy = ql2[il].y;
          const float mx = ml2[il].x, my = ml2[il].y;
          *(unsigned int*)&A[row][0 * 32 + hh2] = pk2(fx * qx, fy * qy);
          *(unsigned int*)&A[row][1 * 32 + hh2] = pk2(fx * mx, fy * my);
          *(unsigned int*)&A[row][2 * 32 + hh2] = pk2(fabsf(fx - qx), fabsf(fy - qy));
          *(unsigned int*)&A[row][3 * 32 + hh2] = pk2(fabsf(fx - mx), fabsf(fy - my));
        }
      }
    }
    if (hc < 7) prefetch(hc + 1);
    __syncthreads();

#pragma unroll
    for (int s = 0; s < 4; ++s) {
      short8 Af[4];
#pragma unroll
      for (int mf = 0; mf < 4; ++mf)
        Af[mf] = *(const short8*)&A[rg * 64 + mf * 16 + l15][s * 32 + q * 8];
#pragma unroll
      for (int mf = 0; mf < 4; ++mf)
#pragma unroll
        for (int nf = 0; nf < 4; ++nf)
          acc[mf][nf] = __builtin_amdgcn_mfma_f32_16x16x32_bf16(Af[mf], Bf[s][nf], acc[mf][nf], 0, 0, 0);
    }
    __syncthreads();
  }

  float psum[4][4];
#pragma unroll
  for (int mf = 0; mf < 4; ++mf)
#pragma unroll
    for (int v = 0; v < 4; ++v) psum[mf][v] = 0.f;

#pragma unroll
  for (int nf = 0; nf < 4; ++nf) {
    const int k = cg * 64 + nf * 16 + l15;
    const float zb = z1b[k], zw = z2w[k];
#pragma unroll
    for (int mf = 0; mf < 4; ++mf)
#pragma unroll
      for (int v = 0; v < 4; ++v) {
        const float x = acc[mf][nf][v] + zb;
        const float e = __expf(2.f * x);
        const float t = 1.f - 2.f / (e + 1.f);  // tanh(x)
        psum[mf][v] += zw * t;
      }
  }
#pragma unroll
  for (int d = 1; d < 16; d <<= 1)
#pragma unroll
    for (int mf = 0; mf < 4; ++mf)
#pragma unroll
      for (int v = 0; v < 4; ++v) psum[mf][v] += __shfl_xor(psum[mf][v], d, 64);
  if (l15 == 0) {
#pragma unroll
    for (int mf = 0; mf < 4; ++mf)
#pragma unroll
      for (int v = 0; v < 4; ++v)
        Gpart[rg * 64 + mf * 16 + q * 4 + v][cg] = psum[mf][v];
  }
  __syncthreads();
  if (tid < 128) {
    const float g = Gpart[tid][0] + Gpart[tid][1] + Gpart[tid][2] + Gpart[tid][3] + z2b[0];
    const int i = i0 + (tid >> 6), j = tid & 63;
    G[(n * SS + i) * SS + j] = g;
  }
}

// ---------------------------------------------------------------------------
// Phase A2: masked softmax over j. One wave per (n,i); lane = j.
// ---------------------------------------------------------------------------
__global__ void softmax_attn(const float* __restrict__ G, const int* __restrict__ doc_len,
                             float* __restrict__ attn) {
  const int gid = blockIdx.x * 256 + threadIdx.x;
  const int wid = gid >> 6, l = gid & 63;
  const int n = wid >> 6, i = wid & 63;
  const int dl = doc_len[n];
  const float g = G[(n * SS + i) * SS + l];
  const float x = (l < dl && g != 0.0f) ? g : -INFINITY;  // matches where(G*mask==0,-inf)
  float mx = x;
#pragma unroll
  for (int d = 1; d < 64; d <<= 1) mx = fmaxf(mx, __shfl_xor(mx, d, 64));
  const float e = (x == -INFINITY) ? 0.f : __expf(x - mx);
  float s = e;
#pragma unroll
  for (int d = 1; d < 64; d <<= 1) s += __shfl_xor(s, d, 64);
  attn[(n * SS + i) * SS + l] = e / s;
}

// ---------------------------------------------------------------------------
// Phase C: GRU-style scan, TWO independent 16-row problems per block (same n,
// i-groups i0 and i0+16). The 64 scans are latency-bound, not BW-bound: with
// one problem the barrier lockstep serializes LDS-read -> MFMA -> VALU phases.
// Interleaving two problems gives each wave two independent dependency chains:
// P1's ds_reads/MFMAs overlap P0's, and P0's transcendental-heavy update
// overlaps P1's MFMA drain. B-fragments (128 VGPR), FWr/FW loads, Ub shared.
// C stored K-PERMUTED (cols h0,h0+16 adjacent) so the update writes one u32
// (v_cvt_pk_bf16_f32) per col-pair; wcatbf/nmbf carry the same K permutation.
// ---------------------------------------------------------------------------
__global__ __launch_bounds__(512, 2) void gru_scan(
    const unsigned short* __restrict__ wcat, const float* __restrict__ FWr,
    const float* __restrict__ FW, const float* __restrict__ Ub,
    const float* __restrict__ attn, unsigned short* __restrict__ Cout) {
  __shared__ unsigned short Cbf[2][2][16 * 264];  // [problem][buf], stride 264 bf16
  __shared__ float attn_sT[2][64 * 16];           // [problem][t][row]

  const int bi = blockIdx.x, n = bi >> 1, i0 = (bi & 1) * 32;
  const int tid = threadIdx.x, w = tid >> 6, l = tid & 63;
  const int l15 = l & 15, q = l >> 4;
  const int h0 = w * 32 + l15;  // lane's first actual h column (second is h0+16)

  // persistent B-fragments (shared by both problems):
  // f=0/1 -> Ur cols h0/h0+16 ; f=2/3 -> U cols h0/h0+16 (K storage-permuted)
  short8 Bf[8][4];
#pragma unroll
  for (int f = 0; f < 4; ++f) {
    const int wrow = ((f >> 1) ? 256 : 0) + w * 32 + (f & 1) * 16 + l15;
    const unsigned short* bb = wcat + wrow * 256 + q * 8;
#pragma unroll
    for (int kt = 0; kt < 8; ++kt)
      Bf[kt][f] = *(const short8*)(bb + kt * 32);
  }

  const float ub0 = Ub[h0], ub1 = Ub[h0 + 16];

  for (int e = tid; e < 64 * 16; e += 512) {
    attn_sT[0][e] = attn[(n * SS + i0 + (e & 15)) * SS + (e >> 4)];
    attn_sT[1][e] = attn[(n * SS + i0 + 16 + (e & 15)) * SS + (e >> 4)];
  }
  for (int e = tid; e < 16 * 132; e += 512) {
    ((unsigned int*)Cbf[0][0])[e] = 0u;
    ((unsigned int*)Cbf[1][0])[e] = 0u;
  }
  __syncthreads();

  const float* fwr_g = FWr + n * SS * HH;
  const float* fw_g  = FW + n * SS * HH;

  // fp32 master state in registers: [problem][colpair][v]
  float cm[2][2][4];
#pragma unroll
  for (int p = 0; p < 2; ++p)
#pragma unroll
    for (int a = 0; a < 2; ++a)
#pragma unroll
      for (int v = 0; v < 4; ++v) cm[p][a][v] = 0.f;

  // pipelined fact-projection scalars (shared across problems)
  float fr0 = fwr_g[h0], fr1 = fwr_g[h0 + 16];
  float fc0 = fw_g[h0],  fc1 = fw_g[h0 + 16];

  for (int t = 0; t < 64; ++t) {
    const int cur = t & 1, nxt = cur ^ 1;

    // P0 A-fragments + MFMA
    short8 Af0[8];
#pragma unroll
    for (int kt = 0; kt < 8; ++kt)
      Af0[kt] = *(const short8*)&Cbf[0][cur][l15 * 264 + kt * 32 + q * 8];

    // prefetch next step's shared FWr/FW (consumed next iteration)
    float nr0 = 0.f, nr1 = 0.f, nc0 = 0.f, nc1 = 0.f;
    if (t < 63) {
      nr0 = fwr_g[(t + 1) * HH + h0];
      nr1 = fwr_g[(t + 1) * HH + h0 + 16];
      nc0 = fw_g[(t + 1) * HH + h0];
      nc1 = fw_g[(t + 1) * HH + h0 + 16];
    }

    const f32x4 z4 = {0.f, 0.f, 0.f, 0.f};
    f32x4 acc0[4], acc1[4];
#pragma unroll
    for (int f = 0; f < 4; ++f) { acc0[f] = z4; acc1[f] = z4; }

    __builtin_amdgcn_s_setprio(1);
#pragma unroll
    for (int kt = 0; kt < 8; ++kt)
#pragma unroll
      for (int f = 0; f < 4; ++f)
        acc0[f] = __builtin_amdgcn_mfma_f32_16x16x32_bf16(Af0[kt], Bf[kt][f], acc0[f], 0, 0, 0);
    __builtin_amdgcn_s_setprio(0);

    // P1 A-fragments + MFMA (reads overlap P0 MFMA drain)
    short8 Af1[8];
#pragma unroll
    for (int kt = 0; kt < 8; ++kt)
      Af1[kt] = *(const short8*)&Cbf[1][cur][l15 * 264 + kt * 32 + q * 8];

    __builtin_amdgcn_s_setprio(1);
#pragma unroll
    for (int kt = 0; kt < 8; ++kt)
#pragma unroll
      for (int f = 0; f < 4; ++f)
        acc1[f] = __builtin_amdgcn_mfma_f32_16x16x32_bf16(Af1[kt], Bf[kt][f], acc1[f], 0, 0, 0);
    __builtin_amdgcn_s_setprio(0);

    const f32x4 gv0 = *(const f32x4*)&attn_sT[0][t * 16 + q * 4];
    const f32x4 gv1 = *(const f32x4*)&attn_sT[1][t * 16 + q * 4];
    unsigned int* cw0 = (unsigned int*)Cbf[0][nxt] + w * 16 + l15;
    unsigned int* cw1 = (unsigned int*)Cbf[1][nxt] + w * 16 + l15;

    // P0 update (VALU; overlaps P1 MFMA drain), then P1 update
#pragma unroll
    for (int v = 0; v < 4; ++v) {
      const int row = q * 4 + v;
      const float g = gv0[v];
      const float r0v = 1.f / (1.f + __expf(-(fr0 + acc0[0][v])));
      const float u0v = acc0[2][v] + ub0;
      const float x0v = fc0 + r0v * u0v;
      const float e0v = __expf(2.f * x0v);
      const float h0v = 1.f - 2.f / (e0v + 1.f);
      const float c0 = cm[0][0][v] + g * (h0v - cm[0][0][v]);
      cm[0][0][v] = c0;
      const float r1v = 1.f / (1.f + __expf(-(fr1 + acc0[1][v])));
      const float u1v = acc0[3][v] + ub1;
      const float x1v = fc1 + r1v * u1v;
      const float e1v = __expf(2.f * x1v);
      const float h1v = 1.f - 2.f / (e1v + 1.f);
      const float c1 = cm[0][1][v] + g * (h1v - cm[0][1][v]);
      cm[0][1][v] = c1;
      unsigned int pr;
      asm("v_cvt_pk_bf16_f32 %0, %1, %2" : "=v"(pr) : "v"(c0), "v"(c1));
      cw0[row * 132] = pr;
    }
#pragma unroll
    for (int v = 0; v < 4; ++v) {
      const int row = q * 4 + v;
      const float g = gv1[v];
      const float r0v = 1.f / (1.f + __expf(-(fr0 + acc1[0][v])));
      const float u0v = acc1[2][v] + ub0;
      const float x0v = fc0 + r0v * u0v;
      const float e0v = __expf(2.f * x0v);
      const float h0v = 1.f - 2.f / (e0v + 1.f);
      const float c0 = cm[1][0][v] + g * (h0v - cm[1][0][v]);
      cm[1][0][v] = c0;
      const float r1v = 1.f / (1.f + __expf(-(fr1 + acc1[1][v])));
      const float u1v = acc1[3][v] + ub1;
      const float x1v = fc1 + r1v * u1v;
      const float e1v = __expf(2.f * x1v);
      const float h1v = 1.f - 2.f / (e1v + 1.f);
      const float c1 = cm[1][1][v] + g * (h1v - cm[1][1][v]);
      cm[1][1][v] = c1;
      unsigned int pr;
      asm("v_cvt_pk_bf16_f32 %0, %1, %2" : "=v"(pr) : "v"(c0), "v"(c1));
      cw1[row * 132] = pr;
    }
    fr0 = nr0; fr1 = nr1; fc0 = nc0; fc1 = nc1;
    __syncthreads();  // single barrier: writes to nxt complete before next reads
  }

  // final C in buffer 0 (t=63 wrote buf 0); written in STORAGE (K-permuted)
  // order -- next_mem_gemm's nmbf middle section carries the same permutation.
  for (int e = tid; e < 16 * 128; e += 512) {
    const int row = e >> 7, wo = e & 127;
    ((unsigned int*)Cout)[(n * SS + i0 + row) * 128 + wo] =
        *(const unsigned int*)&Cbf[0][0][row * 264 + wo * 2];
    ((unsigned int*)Cout)[(n * SS + i0 + 16 + row) * 128 + wo] =
        *(const unsigned int*)&Cbf[1][0][row * 264 + wo * 2];
  }
}

// ---------------------------------------------------------------------------
// Phase D: next_mem = relu([prevM | C | questions] @ nm_w^T + nm_b)
// (cbf and nmbf's middle K-section share the same K permutation -> invariant)
// ---------------------------------------------------------------------------
__global__ __launch_bounds__(256) void next_mem_gemm(
    const unsigned short* __restrict__ pmbf, const unsigned short* __restrict__ cbf,
    const unsigned short* __restrict__ qbf, const unsigned short* __restrict__ nmbf,
    const float* __restrict__ nmb, float* __restrict__ out) {
  __shared__ unsigned short A[64][40];  // stride 40 bf16 (20 words -> 2-way max)
  const int bi = blockIdx.x;
  const int rb = bi >> 2, cb = bi & 3;
  const int r0 = rb * 64, c0 = cb * 64;
  const int tid = threadIdx.x, w = tid >> 6, l = tid & 63;
  const int l15 = l & 15, q = l >> 4;

  f32x4 acc[4];
  const f32x4 z4 = {0.f, 0.f, 0.f, 0.f};
#pragma unroll
  for (int nf = 0; nf < 4; ++nf) acc[nf] = z4;

  for (int kt = 0; kt < 24; ++kt) {
    const int kg = kt * 32;
    const unsigned short* src =
        kg < 256 ? (pmbf + kg) : (kg < 512 ? (cbf + kg - 256) : (qbf + kg - 512));
    const int kk = (tid & 15) * 2;
#pragma unroll
    for (int ps = 0; ps < 4; ++ps) {
      const int row = ps * 16 + (tid >> 4);
      *(unsigned int*)&A[row][kk] = *(const unsigned int*)(src + (r0 + row) * HH + kk);
    }
    __syncthreads();
    short8 Bfr[4];
#pragma unroll
    for (int nf = 0; nf < 4; ++nf)
      Bfr[nf] = *(const short8*)(nmbf + (c0 + nf * 16 + l15) * 768 + kg + q * 8);
    const short8 Af = *(const short8*)&A[w * 16 + l15][q * 8];
#pragma unroll
    for (int nf = 0; nf < 4; ++nf)
      acc[nf] = __builtin_amdgcn_mfma_f32_16x16x32_bf16(Af, Bfr[nf], acc[nf], 0, 0, 0);
    __syncthreads();
  }
#pragma unroll
  for (int nf = 0; nf < 4; ++nf) {
    const int col = c0 + nf * 16 + l15;
    const float bv = nmb[col];
#pragma unroll
    for (int v = 0; v < 4; ++v) {
      const int grow = r0 + w * 16 + q * 4 + v;
      out[grow * HH + col] = fmaxf(acc[nf][v] + bv, 0.f);
    }
  }
}

// ---------------------------------------------------------------------------
extern "C" void kernel_launch(void* const* d_in, const int* in_sizes, int n_in,
                              void* d_out, int out_size, void* d_ws, size_t ws_size,
                              hipStream_t stream) {
  const float* facts     = (const float*)d_in[0];
  const float* prevM     = (const float*)d_in[1];
  const float* questions = (const float*)d_in[2];
  const int*   doc_len   = (const int*)d_in[3];
  const float* z1w = (const float*)d_in[4];
  const float* z1b = (const float*)d_in[5];
  const float* z2w = (const float*)d_in[6];
  const float* z2b = (const float*)d_in[7];
  const float* Wrw = (const float*)d_in[8];
  const float* Wrb = (const float*)d_in[9];
  const float* Urw = (const float*)d_in[10];
  const float* Urb = (const float*)d_in[11];
  const float* Ww  = (const float*)d_in[12];
  const float* Wb  = (const float*)d_in[13];
  const float* Uw  = (const float*)d_in[14];
  const float* Ub  = (const float*)d_in[15];
  const float* nmw = (const float*)d_in[16];
  const float* nmb = (const float*)d_in[17];

  char* ws = (char*)d_ws;
  unsigned short* z1wbf  = (unsigned short*)(ws + 0);        // 512 KB
  unsigned short* wcatbf = (unsigned short*)(ws + 524288);   // 256 KB
  unsigned short* nmbf   = (unsigned short*)(ws + 786432);   // 384 KB
  unsigned short* pmbf   = (unsigned short*)(ws + 1179648);  // 512 KB
  unsigned short* qbf    = (unsigned short*)(ws + 1703936);  // 512 KB
  float* G   = (float*)(ws + 2228224);                       // 256 KB
  float* FWr = (float*)(ws + 2490368);                       // 1 MB
  float* FW  = (float*)(ws + 3538944);                       // 1 MB
  unsigned short* cbf = (unsigned short*)(ws + 4587520);     // 512 KB  (total ~4.9 MB)

  float* out  = (float*)d_out;
  float* attn = out + NB * SS * HH;  // second output region

  prolog_cvt<<<4352, 256, 0, stream>>>(z1w, Urw, Uw, nmw, prevM, questions,
                                       z1wbf, wcatbf, nmbf, pmbf, qbf);
  fact_proj<<<256, 256, 0, stream>>>(facts, Wrw, Wrb, Urb, Ww, Wb, FWr, FW);
  gate_gemm<<<512, 512, 0, stream>>>(facts, prevM, questions, z1wbf, z1b, z2w, z2b, G);
  softmax_attn<<<256, 256, 0, stream>>>(G, doc_len, attn);
  gru_scan<<<32, 512, 0, stream>>>(wcatbf, FWr, FW, Ub, attn, cbf);
  next_mem_gemm<<<64, 256, 0, stream>>>(pmbf, cbf, qbf, nmbf, nmb, out);
}

// Round 3
// 273.352 us; speedup vs baseline: 1.5430x; 1.5430x over previous
//
#include <hip/hip_runtime.h>
#include <hip/hip_bf16.h>
#include <math.h>

#define NB 16
#define SS 64
#define HH 256
#define FAA 256

using short8 = __attribute__((ext_vector_type(8))) short;
using f32x4  = __attribute__((ext_vector_type(4))) float;

__device__ __forceinline__ float bf2f_u(unsigned int u) {
  union { unsigned int u; float f; } x; x.u = u << 16; return x.f;
}
__device__ __forceinline__ unsigned short f2bf(float f) {
  union { float f; unsigned int u; } x; x.f = f;
  unsigned int u = x.u;
  return (unsigned short)((u + 0x7FFFu + ((u >> 16) & 1u)) >> 16);  // RNE
}
__device__ __forceinline__ unsigned int cvtpk(float a, float b) {
  unsigned int r;
  asm("v_cvt_pk_bf16_f32 %0, %1, %2" : "=v"(r) : "v"(a), "v"(b));  // RNE, a->lo b->hi
  return r;
}
// select a[q] without runtime vector indexing (rule: dyn-indexed regs -> scratch)
__device__ __forceinline__ float sel4(const f32x4 a, int q) {
  const float s01 = (q & 1) ? a[1] : a[0];
  const float s23 = (q & 1) ? a[3] : a[2];
  return (q & 2) ? s23 : s01;
}

// ---------------------------------------------------------------------------
// Prolog: fp32 -> bf16 conversions of weights / reused activations.
// wcat layout: rows 0..255 = Ur[o][k], rows 256..511 = U[o-256][k], with the
// K dimension PERMUTED so actual cols (g*32+l, g*32+16+l) sit at storage
// (g*32+2l, g*32+2l+1). gru_scan stores C in the same permuted order, letting
// the update write one u32 (cvt_pk) per col-pair. nmbf's middle K-section
// (cols 256..511 = C) gets the identical permutation so phase D is invariant.
// ---------------------------------------------------------------------------
__global__ void prolog_cvt(const float* __restrict__ z1w, const float* __restrict__ Ur,
                           const float* __restrict__ U, const float* __restrict__ nmw,
                           const float* __restrict__ pm, const float* __restrict__ qs,
                           unsigned short* __restrict__ z1wbf, unsigned short* __restrict__ wcatbf,
                           unsigned short* __restrict__ nmbf, unsigned short* __restrict__ pmbf,
                           unsigned short* __restrict__ qbf) {
  int idx = blockIdx.x * 256 + threadIdx.x;
  if (idx < 262144) { z1wbf[idx] = f2bf(z1w[idx]); return; }
  idx -= 262144;
  if (idx < 131072) {
    int o = idx >> 8, s = idx & 255;
    int t = s & 31;
    int cc = (s & ~31) + (t >> 1) + ((t & 1) << 4);  // storage s -> actual col
    wcatbf[idx] = f2bf(o < 256 ? Ur[o * 256 + cc] : U[(o - 256) * 256 + cc]);
    return;
  }
  idx -= 131072;
  if (idx < 196608) {
    int o = idx / 768, k = idx - o * 768;
    int kk = k;
    if (k >= 256 && k < 512) {
      int s = k - 256, t = s & 31;
      kk = 256 + (s & ~31) + (t >> 1) + ((t & 1) << 4);
    }
    nmbf[idx] = f2bf(nmw[o * 768 + kk]);
    return;
  }
  idx -= 196608;
  if (idx < 262144) { pmbf[idx] = f2bf(pm[idx]); return; }
  idx -= 262144;
  if (idx < 262144) { qbf[idx] = f2bf(qs[idx]); return; }
}

// ---------------------------------------------------------------------------
// Phase B: FWr[b,h] = facts[b]·Wr[h] + Wr_b[h] + Ur_b[h];  FW[b,h] = facts[b]·W[h] + W_b[h]
// ---------------------------------------------------------------------------
__global__ __launch_bounds__(256) void fact_proj(
    const float* __restrict__ facts, const float* __restrict__ Wr, const float* __restrict__ Wrb,
    const float* __restrict__ Urb, const float* __restrict__ Ww, const float* __restrict__ Wb,
    float* __restrict__ FWr, float* __restrict__ FW) {
  __shared__ float fl[4][HH];
  const int b0 = blockIdx.x * 4;
  const int tid = threadIdx.x;
#pragma unroll
  for (int r = 0; r < 4; ++r) fl[r][tid] = facts[(b0 + r) * HH + tid];
  __syncthreads();
  float ar[4] = {0.f, 0.f, 0.f, 0.f}, aw[4] = {0.f, 0.f, 0.f, 0.f};
  const float4* wr = (const float4*)(Wr + tid * HH);
  const float4* ww = (const float4*)(Ww + tid * HH);
  for (int d4 = 0; d4 < 64; ++d4) {
    float4 a = wr[d4], b = ww[d4];
#pragma unroll
    for (int r = 0; r < 4; ++r) {
      float4 f = *(const float4*)&fl[r][d4 * 4];  // LDS broadcast
      ar[r] += a.x * f.x + a.y * f.y + a.z * f.z + a.w * f.w;
      aw[r] += b.x * f.x + b.y * f.y + b.z * f.z + b.w * f.w;
    }
  }
  const float br = Wrb[tid] + Urb[tid], bw = Wb[tid];
#pragma unroll
  for (int r = 0; r < 4; ++r) {
    FWr[(b0 + r) * HH + tid] = ar[r] + br;
    FW[(b0 + r) * HH + tid] = aw[r] + bw;
  }
}

// ---------------------------------------------------------------------------
// Phase A: gate GEMM + FUSED masked softmax. Block = (n, 2 i's).
// z built on the fly into LDS (bf16, hardware cvt_pk), z1_w^T from L2.
// Epilogue: tanh + z2_w reduce -> G, then per-wave masked softmax -> attn.
// ---------------------------------------------------------------------------
__global__ __launch_bounds__(512, 2) void gate_gemm(
    const float* __restrict__ facts, const float* __restrict__ prevM,
    const float* __restrict__ questions, const unsigned short* __restrict__ z1wbf,
    const float* __restrict__ z1b, const float* __restrict__ z2w,
    const float* __restrict__ z2b, const int* __restrict__ doc_len,
    float* __restrict__ attn) {
  __shared__ unsigned short A[128][136];  // stride 136 (68 words, 4 mod 32 -> 2-way max)
  __shared__ float Gpart[128][4];
  const int bi = blockIdx.x;
  const int n = bi >> 5, i0 = (bi & 31) * 2;
  const int tid = threadIdx.x;
  const int w = tid >> 6, l = tid & 63;
  const int rg = w >> 2, cg = w & 3;        // rowgroup (i-local), colgroup
  const int l15 = l & 15, q = l >> 4;
  const int hh2 = (tid & 15) * 2, jb = tid >> 4;  // builder mapping

  const float* fn = facts + n * SS * HH;
  const float* qn = questions + (n * SS + i0) * HH;
  const float* mn = prevM + (n * SS + i0) * HH;

  const f32x4 zero4 = {0.f, 0.f, 0.f, 0.f};
  f32x4 acc[4][4];
#pragma unroll
  for (int a = 0; a < 4; ++a)
#pragma unroll
    for (int b = 0; b < 4; ++b) acc[a][b] = zero4;

  float2 fv0, fv1, qv0, qv1, mv0, mv1;
  auto prefetch = [&](int hc) {
    const int h = hc * 32 + hh2;
    fv0 = *(const float2*)(fn + jb * HH + h);
    fv1 = *(const float2*)(fn + (jb + 32) * HH + h);
    qv0 = *(const float2*)(qn + h);
    qv1 = *(const float2*)(qn + HH + h);
    mv0 = *(const float2*)(mn + h);
    mv1 = *(const float2*)(mn + HH + h);
  };
  prefetch(0);

  for (int hc = 0; hc < 8; ++hc) {
    short8 Bf[4][4];
    const unsigned short* bb = z1wbf + (cg * 64 + l15) * 1024 + hc * 32 + q * 8;
#pragma unroll
    for (int s = 0; s < 4; ++s)
#pragma unroll
      for (int nf = 0; nf < 4; ++nf)
        Bf[s][nf] = *(const short8*)(bb + (nf * 16) * 1024 + s * 256);

    {
      float2 fl2[2] = {fv0, fv1}, ql2[2] = {qv0, qv1}, ml2[2] = {mv0, mv1};
#pragma unroll
      for (int pl = 0; pl < 2; ++pl) {
        const int j = jb + pl * 32;
#pragma unroll
        for (int il = 0; il < 2; ++il) {
          const int row = il * 64 + j;
          const float fx = fl2[pl].x, fy = fl2[pl].y;
          const float qx = ql2[il].x, qy = ql2[il].y;
          const float mx = ml2[il].x, my = ml2[il].y;
          *(unsigned int*)&A[row][0 * 32 + hh2] = cvtpk(fx * qx, fy * qy);
          *(unsigned int*)&A[row][1 * 32 + hh2] = cvtpk(fx * mx, fy * my);
          *(unsigned int*)&A[row][2 * 32 + hh2] = cvtpk(fabsf(fx - qx), fabsf(fy - qy));
          *(unsigned int*)&A[row][3 * 32 + hh2] = cvtpk(fabsf(fx - mx), fabsf(fy - my));
        }
      }
    }
    if (hc < 7) prefetch(hc + 1);
    __syncthreads();

#pragma unroll
    for (int s = 0; s < 4; ++s) {
      short8 Af[4];
#pragma unroll
      for (int mf = 0; mf < 4; ++mf)
        Af[mf] = *(const short8*)&A[rg * 64 + mf * 16 + l15][s * 32 + q * 8];
#pragma unroll
      for (int mf = 0; mf < 4; ++mf)
#pragma unroll
        for (int nf = 0; nf < 4; ++nf)
          acc[mf][nf] = __builtin_amdgcn_mfma_f32_16x16x32_bf16(Af[mf], Bf[s][nf], acc[mf][nf], 0, 0, 0);
    }
    __syncthreads();
  }

  float psum[4][4];
#pragma unroll
  for (int mf = 0; mf < 4; ++mf)
#pragma unroll
    for (int v = 0; v < 4; ++v) psum[mf][v] = 0.f;

#pragma unroll
  for (int nf = 0; nf < 4; ++nf) {
    const int k = cg * 64 + nf * 16 + l15;
    const float zb = z1b[k], zw = z2w[k];
#pragma unroll
    for (int mf = 0; mf < 4; ++mf)
#pragma unroll
      for (int v = 0; v < 4; ++v) {
        const float x = acc[mf][nf][v] + zb;
        const float e = __expf(2.f * x);
        const float t = 1.f - 2.f / (e + 1.f);  // tanh(x)
        psum[mf][v] += zw * t;
      }
  }
#pragma unroll
  for (int d = 1; d < 16; d <<= 1)
#pragma unroll
    for (int mf = 0; mf < 4; ++mf)
#pragma unroll
      for (int v = 0; v < 4; ++v) psum[mf][v] += __shfl_xor(psum[mf][v], d, 64);
  if (l15 == 0) {
#pragma unroll
    for (int mf = 0; mf < 4; ++mf)
#pragma unroll
      for (int v = 0; v < 4; ++v)
        Gpart[rg * 64 + mf * 16 + q * 4 + v][cg] = psum[mf][v];
  }
  __syncthreads();
  if (tid < 128) {  // waves 0,1 fully active: wave = row i, lane = j
    const float gg = Gpart[tid][0] + Gpart[tid][1] + Gpart[tid][2] + Gpart[tid][3] + z2b[0];
    const int i = i0 + (tid >> 6), j = tid & 63;
    const int dl = doc_len[n];
    const float x = (j < dl && gg != 0.0f) ? gg : -INFINITY;  // where(G*mask==0,-inf)
    float mx = x;
#pragma unroll
    for (int d = 1; d < 64; d <<= 1) mx = fmaxf(mx, __shfl_xor(mx, d, 64));
    const float e = (x == -INFINITY) ? 0.f : __expf(x - mx);
    float s = e;
#pragma unroll
    for (int d = 1; d < 64; d <<= 1) s += __shfl_xor(s, d, 64);
    attn[(n * SS + i) * SS + j] = e / s;
  }
}

// ---------------------------------------------------------------------------
// Phase C: GRU-style scan. Rows are INDEPENDENT scans -> block = (n, 4 rows),
// grid = 256 blocks = ALL 256 CUs (was 64; scan is VALU-throughput-bound on
// active CUs). LDS C tile holds 4 rows; every lane reads A-row (l15&3) -> a
// 4-way same-address broadcast (free), so MFMA computes Y with rows dup'd 4x
// and acc[nf][v] = Y[v][col] on every q-group. Lane (q,l15) updates row q only
// (select v=q, 3 cndmasks) -> 2 cells/lane/step (was 8): 4x less VALU per CU.
// cm state in 2 regs; one barrier/step; C bf16 double-buffered in LDS (5.4KB).
// C stored K-PERMUTED (cols h,h+16 adjacent -> one cvt_pk u32 write);
// wcatbf/nmbf carry the same K permutation.
// ---------------------------------------------------------------------------
__global__ __launch_bounds__(512, 2) void gru_scan(
    const unsigned short* __restrict__ wcat, const float* __restrict__ FWr,
    const float* __restrict__ FW, const float* __restrict__ Ub,
    const float* __restrict__ attn, unsigned short* __restrict__ Cout) {
  __shared__ unsigned short Cbf[2][4 * 272];  // stride 272 sh = 136 dw (8 mod 32 -> 2-way)
  __shared__ float attn_sT[64 * 4];           // [t][row]

  const int bi = blockIdx.x, n = bi >> 4, i0 = (bi & 15) * 4;
  const int tid = threadIdx.x, w = tid >> 6, l = tid & 63;
  const int l15 = l & 15, q = l >> 4;
  const int h0 = w * 32 + l15;  // lane's actual h cols: h0 and h0+16

  // persistent B-fragments: f=0/1 -> Ur cols h0/h0+16 ; f=2/3 -> U cols (K perm'd)
  short8 Bf[8][4];
#pragma unroll
  for (int f = 0; f < 4; ++f) {
    const int wrow = ((f >> 1) ? 256 : 0) + w * 32 + (f & 1) * 16 + l15;
    const unsigned short* bb = wcat + wrow * 256 + q * 8;
#pragma unroll
    for (int kt = 0; kt < 8; ++kt)
      Bf[kt][f] = *(const short8*)(bb + kt * 32);
  }

  const float ub0 = Ub[h0], ub1 = Ub[h0 + 16];

  for (int e = tid; e < 64 * 4; e += 512)  // attn transposed: [t][row]
    attn_sT[e] = attn[(n * SS + i0 + (e & 3)) * SS + (e >> 2)];
  for (int e = tid; e < 544; e += 512)
    ((unsigned int*)Cbf[0])[e] = 0u;
  __syncthreads();

  const float* fwr_g = FWr + n * SS * HH;
  const float* fw_g  = FW + n * SS * HH;

  float cm0 = 0.f, cm1 = 0.f;  // fp32 master state: (row q, h0) and (row q, h0+16)
  float fr0 = fwr_g[h0], fr1 = fwr_g[h0 + 16];
  float fc0 = fw_g[h0],  fc1 = fw_g[h0 + 16];

  for (int t = 0; t < 64; ++t) {
    const int cur = t & 1;
    const unsigned short* Cr = Cbf[cur];
    unsigned int* Cw = (unsigned int*)Cbf[cur ^ 1];

    // A-fragments: row (l15&3) -> 4-way broadcast read, rows duplicated in MFMA
    short8 Af[8];
    const int arow = (l15 & 3) * 272;
#pragma unroll
    for (int kt = 0; kt < 8; ++kt)
      Af[kt] = *(const short8*)&Cr[arow + kt * 32 + q * 8];

    // prefetch next step's FWr/FW (consumed next iteration -> latency hidden)
    float nr0 = 0.f, nr1 = 0.f, nc0 = 0.f, nc1 = 0.f;
    if (t < 63) {
      nr0 = fwr_g[(t + 1) * HH + h0];
      nr1 = fwr_g[(t + 1) * HH + h0 + 16];
      nc0 = fw_g[(t + 1) * HH + h0];
      nc1 = fw_g[(t + 1) * HH + h0 + 16];
    }

    const f32x4 z4 = {0.f, 0.f, 0.f, 0.f};
    f32x4 acc[4];
#pragma unroll
    for (int f = 0; f < 4; ++f) acc[f] = z4;
    __builtin_amdgcn_s_setprio(1);
#pragma unroll
    for (int kt = 0; kt < 8; ++kt)
#pragma unroll
      for (int f = 0; f < 4; ++f)
        acc[f] = __builtin_amdgcn_mfma_f32_16x16x32_bf16(Af[kt], Bf[kt][f], acc[f], 0, 0, 0);
    __builtin_amdgcn_s_setprio(0);

    // every lane holds Y[v][its cols] for all 4 rows; this lane updates row q
    const float yr0 = sel4(acc[0], q), yr1 = sel4(acc[1], q);
    const float yu0 = sel4(acc[2], q), yu1 = sel4(acc[3], q);
    const float g = attn_sT[t * 4 + q];  // 16-lane broadcast

    const float r0 = 1.f / (1.f + __expf(-(fr0 + yr0)));
    const float x0 = fc0 + r0 * (yu0 + ub0);
    const float e0 = __expf(2.f * x0);
    const float h0t = 1.f - 2.f / (e0 + 1.f);
    cm0 += g * (h0t - cm0);

    const float r1 = 1.f / (1.f + __expf(-(fr1 + yr1)));
    const float x1 = fc1 + r1 * (yu1 + ub1);
    const float e1 = __expf(2.f * x1);
    const float h1t = 1.f - 2.f / (e1 + 1.f);
    cm1 += g * (h1t - cm1);

    Cw[q * 136 + w * 16 + l15] = cvtpk(cm0, cm1);  // storage cols (2*l15, 2*l15+1)

    fr0 = nr0; fr1 = nr1; fc0 = nc0; fc1 = nc1;
    __syncthreads();  // single barrier: C writes complete before next Af reads
  }

  // final state in Cbf[0] (t=63 wrote buf 0); 4 rows x 128 dwords = 512 dwords
  {
    const int row = tid >> 7, wo = tid & 127;
    ((unsigned int*)Cout)[(n * SS + i0 + row) * 128 + wo] =
        *(const unsigned int*)&Cbf[0][row * 272 + wo * 2];
  }
}

// ---------------------------------------------------------------------------
// Phase D: next_mem = relu([prevM | C | questions] @ nm_w^T + nm_b)
// (cbf and nmbf's middle K-section share the same K permutation -> invariant)
// ---------------------------------------------------------------------------
__global__ __launch_bounds__(256) void next_mem_gemm(
    const unsigned short* __restrict__ pmbf, const unsigned short* __restrict__ cbf,
    const unsigned short* __restrict__ qbf, const unsigned short* __restrict__ nmbf,
    const float* __restrict__ nmb, float* __restrict__ out) {
  __shared__ unsigned short A[64][40];  // stride 40 bf16 (20 words -> 2-way max)
  const int bi = blockIdx.x;
  const int rb = bi >> 2, cb = bi & 3;
  const int r0 = rb * 64, c0 = cb * 64;
  const int tid = threadIdx.x, w = tid >> 6, l = tid & 63;
  const int l15 = l & 15, q = l >> 4;

  f32x4 acc[4];
  const f32x4 z4 = {0.f, 0.f, 0.f, 0.f};
#pragma unroll
  for (int nf = 0; nf < 4; ++nf) acc[nf] = z4;

  for (int kt = 0; kt < 24; ++kt) {
    const int kg = kt * 32;
    const unsigned short* src =
        kg < 256 ? (pmbf + kg) : (kg < 512 ? (cbf + kg - 256) : (qbf + kg - 512));
    const int kk = (tid & 15) * 2;
#pragma unroll
    for (int ps = 0; ps < 4; ++ps) {
      const int row = ps * 16 + (tid >> 4);
      *(unsigned int*)&A[row][kk] = *(const unsigned int*)(src + (r0 + row) * HH + kk);
    }
    __syncthreads();
    short8 Bfr[4];
#pragma unroll
    for (int nf = 0; nf < 4; ++nf)
      Bfr[nf] = *(const short8*)(nmbf + (c0 + nf * 16 + l15) * 768 + kg + q * 8);
    const short8 Af = *(const short8*)&A[w * 16 + l15][q * 8];
#pragma unroll
    for (int nf = 0; nf < 4; ++nf)
      acc[nf] = __builtin_amdgcn_mfma_f32_16x16x32_bf16(Af, Bfr[nf], acc[nf], 0, 0, 0);
    __syncthreads();
  }
#pragma unroll
  for (int nf = 0; nf < 4; ++nf) {
    const int col = c0 + nf * 16 + l15;
    const float bv = nmb[col];
#pragma unroll
    for (int v = 0; v < 4; ++v) {
      const int grow = r0 + w * 16 + q * 4 + v;
      out[grow * HH + col] = fmaxf(acc[nf][v] + bv, 0.f);
    }
  }
}

// ---------------------------------------------------------------------------
extern "C" void kernel_launch(void* const* d_in, const int* in_sizes, int n_in,
                              void* d_out, int out_size, void* d_ws, size_t ws_size,
                              hipStream_t stream) {
  const float* facts     = (const float*)d_in[0];
  const float* prevM     = (const float*)d_in[1];
  const float* questions = (const float*)d_in[2];
  const int*   doc_len   = (const int*)d_in[3];
  const float* z1w = (const float*)d_in[4];
  const float* z1b = (const float*)d_in[5];
  const float* z2w = (const float*)d_in[6];
  const float* z2b = (const float*)d_in[7];
  const float* Wrw = (const float*)d_in[8];
  const float* Wrb = (const float*)d_in[9];
  const float* Urw = (const float*)d_in[10];
  const float* Urb = (const float*)d_in[11];
  const float* Ww  = (const float*)d_in[12];
  const float* Wb  = (const float*)d_in[13];
  const float* Uw  = (const float*)d_in[14];
  const float* Ub  = (const float*)d_in[15];
  const float* nmw = (const float*)d_in[16];
  const float* nmb = (const float*)d_in[17];

  char* ws = (char*)d_ws;
  unsigned short* z1wbf  = (unsigned short*)(ws + 0);        // 512 KB
  unsigned short* wcatbf = (unsigned short*)(ws + 524288);   // 256 KB
  unsigned short* nmbf   = (unsigned short*)(ws + 786432);   // 384 KB
  unsigned short* pmbf   = (unsigned short*)(ws + 1179648);  // 512 KB
  unsigned short* qbf    = (unsigned short*)(ws + 1703936);  // 512 KB
  float* FWr = (float*)(ws + 2490368);                       // 1 MB
  float* FW  = (float*)(ws + 3538944);                       // 1 MB
  unsigned short* cbf = (unsigned short*)(ws + 4587520);     // 512 KB  (total ~4.9 MB)

  float* out  = (float*)d_out;
  float* attn = out + NB * SS * HH;  // second output region

  prolog_cvt<<<4352, 256, 0, stream>>>(z1w, Urw, Uw, nmw, prevM, questions,
                                       z1wbf, wcatbf, nmbf, pmbf, qbf);
  fact_proj<<<256, 256, 0, stream>>>(facts, Wrw, Wrb, Urb, Ww, Wb, FWr, FW);
  gate_gemm<<<512, 512, 0, stream>>>(facts, prevM, questions, z1wbf, z1b, z2w, z2b,
                                     doc_len, attn);
  gru_scan<<<256, 512, 0, stream>>>(wcatbf, FWr, FW, Ub, attn, cbf);
  next_mem_gemm<<<64, 256, 0, stream>>>(pmbf, cbf, qbf, nmbf, nmb, out);
}

// Round 4
// 244.769 us; speedup vs baseline: 1.7232x; 1.1168x over previous
//
#include <hip/hip_runtime.h>
#include <hip/hip_bf16.h>
#include <math.h>

#define NB 16
#define SS 64
#define HH 256
#define FAA 256

using short8 = __attribute__((ext_vector_type(8))) short;
using f32x4  = __attribute__((ext_vector_type(4))) float;

__device__ __forceinline__ unsigned short f2bf(float f) {
  union { float f; unsigned int u; } x; x.f = f;
  unsigned int u = x.u;
  return (unsigned short)((u + 0x7FFFu + ((u >> 16) & 1u)) >> 16);  // RNE
}
__device__ __forceinline__ unsigned int cvtpk(float a, float b) {
  unsigned int r;
  asm("v_cvt_pk_bf16_f32 %0, %1, %2" : "=v"(r) : "v"(a), "v"(b));  // RNE, a->lo b->hi
  return r;
}
// select a[q] without runtime vector indexing (dyn-indexed regs -> scratch)
__device__ __forceinline__ float sel4(const f32x4 a, int q) {
  const float s01 = (q & 1) ? a[1] : a[0];
  const float s23 = (q & 1) ? a[3] : a[2];
  return (q & 2) ? s23 : s01;
}

// ---------------------------------------------------------------------------
// Prolog: fp32 -> bf16 conversions of weights / reused activations.
// wcat layout: rows 0..255 = Ur[o][k], rows 256..511 = U[o-256][k], with the
// K dimension PERMUTED so actual cols (g*32+l, g*32+16+l) sit at storage
// (g*32+2l, g*32+2l+1). gru_scan stores C in the same permuted order, letting
// the update write one u32 (cvt_pk) per col-pair. nmbf's middle K-section
// (cols 256..511 = C) gets the identical permutation so phase D is invariant.
// ---------------------------------------------------------------------------
__global__ void prolog_cvt(const float* __restrict__ z1w, const float* __restrict__ Ur,
                           const float* __restrict__ U, const float* __restrict__ nmw,
                           const float* __restrict__ pm, const float* __restrict__ qs,
                           unsigned short* __restrict__ z1wbf, unsigned short* __restrict__ wcatbf,
                           unsigned short* __restrict__ nmbf, unsigned short* __restrict__ pmbf,
                           unsigned short* __restrict__ qbf) {
  int idx = blockIdx.x * 256 + threadIdx.x;
  if (idx < 262144) { z1wbf[idx] = f2bf(z1w[idx]); return; }
  idx -= 262144;
  if (idx < 131072) {
    int o = idx >> 8, s = idx & 255;
    int t = s & 31;
    int cc = (s & ~31) + (t >> 1) + ((t & 1) << 4);  // storage s -> actual col
    wcatbf[idx] = f2bf(o < 256 ? Ur[o * 256 + cc] : U[(o - 256) * 256 + cc]);
    return;
  }
  idx -= 131072;
  if (idx < 196608) {
    int o = idx / 768, k = idx - o * 768;
    int kk = k;
    if (k >= 256 && k < 512) {
      int s = k - 256, t = s & 31;
      kk = 256 + (s & ~31) + (t >> 1) + ((t & 1) << 4);
    }
    nmbf[idx] = f2bf(nmw[o * 768 + kk]);
    return;
  }
  idx -= 196608;
  if (idx < 262144) { pmbf[idx] = f2bf(pm[idx]); return; }
  idx -= 262144;
  if (idx < 262144) { qbf[idx] = f2bf(qs[idx]); return; }
}

// ---------------------------------------------------------------------------
// Phase B: FWr[b,h] = facts[b]·Wr[h] + Wr_b[h] + Ur_b[h];  FW[b,h] = facts[b]·W[h] + W_b[h]
// ---------------------------------------------------------------------------
__global__ __launch_bounds__(256) void fact_proj(
    const float* __restrict__ facts, const float* __restrict__ Wr, const float* __restrict__ Wrb,
    const float* __restrict__ Urb, const float* __restrict__ Ww, const float* __restrict__ Wb,
    float* __restrict__ FWr, float* __restrict__ FW) {
  __shared__ float fl[4][HH];
  const int b0 = blockIdx.x * 4;
  const int tid = threadIdx.x;
#pragma unroll
  for (int r = 0; r < 4; ++r) fl[r][tid] = facts[(b0 + r) * HH + tid];
  __syncthreads();
  float ar[4] = {0.f, 0.f, 0.f, 0.f}, aw[4] = {0.f, 0.f, 0.f, 0.f};
  const float4* wr = (const float4*)(Wr + tid * HH);
  const float4* ww = (const float4*)(Ww + tid * HH);
  for (int d4 = 0; d4 < 64; ++d4) {
    float4 a = wr[d4], b = ww[d4];
#pragma unroll
    for (int r = 0; r < 4; ++r) {
      float4 f = *(const float4*)&fl[r][d4 * 4];  // LDS broadcast
      ar[r] += a.x * f.x + a.y * f.y + a.z * f.z + a.w * f.w;
      aw[r] += b.x * f.x + b.y * f.y + b.z * f.z + b.w * f.w;
    }
  }
  const float br = Wrb[tid] + Urb[tid], bw = Wb[tid];
#pragma unroll
  for (int r = 0; r < 4; ++r) {
    FWr[(b0 + r) * HH + tid] = ar[r] + br;
    FW[(b0 + r) * HH + tid] = aw[r] + bw;
  }
}

// ---------------------------------------------------------------------------
// Phase A: gate GEMM + FUSED masked softmax. Block = (n, 2 i's) = 128 rows,
// 256 cols, K=1024 processed as 32 chunks of 32 (hc outer, section s inner;
// accumulation order identical to previous version -> bit-identical output).
// RESTRUCTURED (was VGPR-starved, latency-exposed; MfmaUtil 15%):
//  - B chunk (256x32k, 16KB) staged via global_load_lds width=16 (no VGPR
//    round-trip, latency overlapped with compute of previous chunk)
//  - A chunk (128x32k, 8KB) built by VALU from register-prefetched f/q/m
//  - both double-buffered -> ONE barrier per chunk
//  - 16B-slot XOR swizzle (slot ^= rowcol&3) on all LDS writes+reads ->
//    ds_read_b128 / b32 writes are 2-way max (free)
//  - launch_bounds(512,4) -> 2 blocks/CU (was 1): cross-block overlap fills
//    barrier gaps (m114)
// ---------------------------------------------------------------------------
__global__ __launch_bounds__(512, 4) void gate_gemm(
    const float* __restrict__ facts, const float* __restrict__ prevM,
    const float* __restrict__ questions, const unsigned short* __restrict__ z1wbf,
    const float* __restrict__ z1b, const float* __restrict__ z2w,
    const float* __restrict__ z2b, const int* __restrict__ doc_len,
    float* __restrict__ attn) {
  __shared__ unsigned short Ab[2][128 * 32];  // 8KB per buf
  __shared__ unsigned short Bb[2][256 * 32];  // 16KB per buf
  __shared__ float Gpart[128][4];

  const int bi = blockIdx.x;
  const int n = bi >> 5, i0 = (bi & 31) * 2;
  const int tid = threadIdx.x;
  const int w = tid >> 6, l = tid & 63;
  const int rg = w >> 2, cg = w & 3;        // rowgroup (2), colgroup (4)
  const int l15 = l & 15, q = l >> 4;
  const int t15 = tid & 15, jb = tid >> 4;  // builder mapping (jb 0..31)

  const float* fn = facts + n * SS * HH;
  const float* qn = questions + (n * SS + i0) * HH;
  const float* mn = prevM + (n * SS + i0) * HH;

  // stage B chunk (hc,s) into Bb[buf]: wave w covers cols w*32..w*32+31.
  // LDS linear by lane; k-slot pre-swizzled on the GLOBAL side (T2 pattern).
  auto stageB = [&](int buf, int hc, int s) {
    const int kb = s * 256 + hc * 32;
    const int swz = ((l & 3) ^ ((l >> 2) & 3)) * 8;  // colg&3 == (l>>2)&3
#pragma unroll
    for (int j = 0; j < 2; ++j) {
      const int colg = w * 32 + j * 16 + (l >> 2);
      const unsigned short* src = z1wbf + colg * 1024 + kb + swz;
      __builtin_amdgcn_global_load_lds(src, Bb[buf] + (w * 32 + j * 16) * 32, 16, 0, 0);
    }
  };

  // build A chunk section s into Ab[buf] from prefetched f/q/m registers
  auto buildA = [&](int buf, int s, float2 f0, float2 f1, float2 q0, float2 q1,
                    float2 m0, float2 m1) {
    unsigned int* dst = (unsigned int*)Ab[buf];
    const int dsw = t15 ^ ((jb & 3) << 2);  // swizzled 4B-slot (row&3 == jb&3)
    const float2 o0 = (s & 1) ? m0 : q0;
    const float2 o1 = (s & 1) ? m1 : q1;
#pragma unroll
    for (int pl = 0; pl < 2; ++pl) {
      const float fx = pl ? f1.x : f0.x;
      const float fy = pl ? f1.y : f0.y;
#pragma unroll
      for (int il = 0; il < 2; ++il) {
        const int row = il * 64 + pl * 32 + jb;
        const float ox = il ? o1.x : o0.x;
        const float oy = il ? o1.y : o0.y;
        float a, b;
        if (s < 2) { a = fx * ox;         b = fy * oy; }
        else       { a = fabsf(fx - ox);  b = fabsf(fy - oy); }
        dst[row * 16 + dsw] = cvtpk(a, b);
      }
    }
  };

  const f32x4 zero4 = {0.f, 0.f, 0.f, 0.f};
  f32x4 acc[4][4];
#pragma unroll
  for (int a = 0; a < 4; ++a)
#pragma unroll
    for (int b = 0; b < 4; ++b) acc[a][b] = zero4;

  // MFMA on chunk in buf: Bf cached 4-deep, Af just-in-time (reg pressure)
  auto mfmaStep = [&](int buf) {
    short8 Bfr[4];
#pragma unroll
    for (int nf = 0; nf < 4; ++nf) {
      const int col = cg * 64 + nf * 16 + l15;
      Bfr[nf] = *(const short8*)&Bb[buf][col * 32 + (q ^ (l15 & 3)) * 8];
    }
    __builtin_amdgcn_s_setprio(1);
#pragma unroll
    for (int mf = 0; mf < 4; ++mf) {
      const int row = rg * 64 + mf * 16 + l15;
      const short8 Afm = *(const short8*)&Ab[buf][row * 32 + (q ^ (l15 & 3)) * 8];
#pragma unroll
      for (int nf = 0; nf < 4; ++nf)
        acc[mf][nf] = __builtin_amdgcn_mfma_f32_16x16x32_bf16(Afm, Bfr[nf], acc[mf][nf], 0, 0, 0);
    }
    __builtin_amdgcn_s_setprio(0);
  };

  const int hh2 = t15 * 2;
  auto pf = [&](int hc, float2& f0, float2& f1, float2& q0, float2& q1,
                float2& m0, float2& m1) {
    const int h = hc * 32 + hh2;
    f0 = *(const float2*)(fn + jb * HH + h);
    f1 = *(const float2*)(fn + (jb + 32) * HH + h);
    q0 = *(const float2*)(qn + h);
    q1 = *(const float2*)(qn + HH + h);
    m0 = *(const float2*)(mn + h);
    m1 = *(const float2*)(mn + HH + h);
  };

  float2 Rf0, Rf1, Rq0, Rq1, Rm0, Rm1;    // current hc operands
  float2 Sf0, Sf1, Sq0, Sq1, Sm0, Sm1;    // next hc operands
  pf(0, Rf0, Rf1, Rq0, Rq1, Rm0, Rm1);
  stageB(0, 0, 0);
  buildA(0, 0, Rf0, Rf1, Rq0, Rq1, Rm0, Rm1);
  __syncthreads();

  int buf = 0;
  for (int hc = 0; hc < 8; ++hc) {
    // sub 0: compute (hc,0); prep (hc,1)
    stageB(buf ^ 1, hc, 1);
    buildA(buf ^ 1, 1, Rf0, Rf1, Rq0, Rq1, Rm0, Rm1);
    mfmaStep(buf);
    __syncthreads();
    buf ^= 1;
    // sub 1: compute (hc,1); prep (hc,2)
    stageB(buf ^ 1, hc, 2);
    buildA(buf ^ 1, 2, Rf0, Rf1, Rq0, Rq1, Rm0, Rm1);
    mfmaStep(buf);
    __syncthreads();
    buf ^= 1;
    // sub 2: compute (hc,2); prep (hc,3); prefetch next hc's f/q/m
    stageB(buf ^ 1, hc, 3);
    buildA(buf ^ 1, 3, Rf0, Rf1, Rq0, Rq1, Rm0, Rm1);
    if (hc < 7) pf(hc + 1, Sf0, Sf1, Sq0, Sq1, Sm0, Sm1);
    mfmaStep(buf);
    __syncthreads();
    buf ^= 1;
    // sub 3: compute (hc,3); prep (hc+1,0) from next-hc regs
    if (hc < 7) {
      stageB(buf ^ 1, hc + 1, 0);
      buildA(buf ^ 1, 0, Sf0, Sf1, Sq0, Sq1, Sm0, Sm1);
    }
    mfmaStep(buf);
    __syncthreads();
    buf ^= 1;
    Rf0 = Sf0; Rf1 = Sf1; Rq0 = Sq0; Rq1 = Sq1; Rm0 = Sm0; Rm1 = Sm1;
  }

  // epilogue: tanh, scale by z2_w, reduce over k
  float psum[4][4];
#pragma unroll
  for (int mf = 0; mf < 4; ++mf)
#pragma unroll
    for (int v = 0; v < 4; ++v) psum[mf][v] = 0.f;

#pragma unroll
  for (int nf = 0; nf < 4; ++nf) {
    const int k = cg * 64 + nf * 16 + l15;
    const float zb = z1b[k], zw = z2w[k];
#pragma unroll
    for (int mf = 0; mf < 4; ++mf)
#pragma unroll
      for (int v = 0; v < 4; ++v) {
        const float x = acc[mf][nf][v] + zb;
        const float e = __expf(2.f * x);
        const float t = 1.f - 2.f / (e + 1.f);  // tanh(x)
        psum[mf][v] += zw * t;
      }
  }
#pragma unroll
  for (int d = 1; d < 16; d <<= 1)
#pragma unroll
    for (int mf = 0; mf < 4; ++mf)
#pragma unroll
      for (int v = 0; v < 4; ++v) psum[mf][v] += __shfl_xor(psum[mf][v], d, 64);
  if (l15 == 0) {
#pragma unroll
    for (int mf = 0; mf < 4; ++mf)
#pragma unroll
      for (int v = 0; v < 4; ++v)
        Gpart[rg * 64 + mf * 16 + q * 4 + v][cg] = psum[mf][v];
  }
  __syncthreads();
  if (tid < 128) {  // waves 0,1 fully active: wave = row i, lane = j
    const float gg = Gpart[tid][0] + Gpart[tid][1] + Gpart[tid][2] + Gpart[tid][3] + z2b[0];
    const int i = i0 + (tid >> 6), j = tid & 63;
    const int dl = doc_len[n];
    const float x = (j < dl && gg != 0.0f) ? gg : -INFINITY;  // where(G*mask==0,-inf)
    float mx = x;
#pragma unroll
    for (int d = 1; d < 64; d <<= 1) mx = fmaxf(mx, __shfl_xor(mx, d, 64));
    const float e = (x == -INFINITY) ? 0.f : __expf(x - mx);
    float s = e;
#pragma unroll
    for (int d = 1; d < 64; d <<= 1) s += __shfl_xor(s, d, 64);
    attn[(n * SS + i) * SS + j] = e / s;
  }
}

// ---------------------------------------------------------------------------
// Phase C: GRU-style scan. Rows are INDEPENDENT scans -> block = (n, 4 rows),
// grid = 256 blocks = ALL 256 CUs. LDS C tile holds 4 rows; every lane reads
// A-row (l15&3) -> 4-way same-address broadcast (free), so MFMA computes Y
// with rows dup'd 4x and acc[nf][v] = Y[v][col] on every q-group. Lane (q,l15)
// updates row q only -> 2 cells/lane/step. cm state in 2 regs; one barrier per
// step; C bf16 double-buffered in LDS. C stored K-PERMUTED (cols h,h+16
// adjacent -> one cvt_pk u32 write); wcatbf/nmbf carry the same permutation.
// ---------------------------------------------------------------------------
__global__ __launch_bounds__(512, 2) void gru_scan(
    const unsigned short* __restrict__ wcat, const float* __restrict__ FWr,
    const float* __restrict__ FW, const float* __restrict__ Ub,
    const float* __restrict__ attn, unsigned short* __restrict__ Cout) {
  __shared__ unsigned short Cbf[2][4 * 272];  // stride 272 sh = 136 dw (8 mod 32 -> 2-way)
  __shared__ float attn_sT[64 * 4];           // [t][row]

  const int bi = blockIdx.x, n = bi >> 4, i0 = (bi & 15) * 4;
  const int tid = threadIdx.x, w = tid >> 6, l = tid & 63;
  const int l15 = l & 15, q = l >> 4;
  const int h0 = w * 32 + l15;  // lane's actual h cols: h0 and h0+16

  // persistent B-fragments: f=0/1 -> Ur cols h0/h0+16 ; f=2/3 -> U cols (K perm'd)
  short8 Bf[8][4];
#pragma unroll
  for (int f = 0; f < 4; ++f) {
    const int wrow = ((f >> 1) ? 256 : 0) + w * 32 + (f & 1) * 16 + l15;
    const unsigned short* bb = wcat + wrow * 256 + q * 8;
#pragma unroll
    for (int kt = 0; kt < 8; ++kt)
      Bf[kt][f] = *(const short8*)(bb + kt * 32);
  }

  const float ub0 = Ub[h0], ub1 = Ub[h0 + 16];

  for (int e = tid; e < 64 * 4; e += 512)  // attn transposed: [t][row]
    attn_sT[e] = attn[(n * SS + i0 + (e & 3)) * SS + (e >> 2)];
  for (int e = tid; e < 544; e += 512)
    ((unsigned int*)Cbf[0])[e] = 0u;
  __syncthreads();

  const float* fwr_g = FWr + n * SS * HH;
  const float* fw_g  = FW + n * SS * HH;

  float cm0 = 0.f, cm1 = 0.f;  // fp32 master state: (row q, h0) and (row q, h0+16)
  float fr0 = fwr_g[h0], fr1 = fwr_g[h0 + 16];
  float fc0 = fw_g[h0],  fc1 = fw_g[h0 + 16];

  for (int t = 0; t < 64; ++t) {
    const int cur = t & 1;
    const unsigned short* Cr = Cbf[cur];
    unsigned int* Cw = (unsigned int*)Cbf[cur ^ 1];

    // A-fragments: row (l15&3) -> 4-way broadcast read, rows duplicated in MFMA
    short8 Af[8];
    const int arow = (l15 & 3) * 272;
#pragma unroll
    for (int kt = 0; kt < 8; ++kt)
      Af[kt] = *(const short8*)&Cr[arow + kt * 32 + q * 8];

    // prefetch next step's FWr/FW (consumed next iteration -> latency hidden)
    float nr0 = 0.f, nr1 = 0.f, nc0 = 0.f, nc1 = 0.f;
    if (t < 63) {
      nr0 = fwr_g[(t + 1) * HH + h0];
      nr1 = fwr_g[(t + 1) * HH + h0 + 16];
      nc0 = fw_g[(t + 1) * HH + h0];
      nc1 = fw_g[(t + 1) * HH + h0 + 16];
    }

    const f32x4 z4 = {0.f, 0.f, 0.f, 0.f};
    f32x4 acc[4];
#pragma unroll
    for (int f = 0; f < 4; ++f) acc[f] = z4;
    __builtin_amdgcn_s_setprio(1);
#pragma unroll
    for (int kt = 0; kt < 8; ++kt)
#pragma unroll
      for (int f = 0; f < 4; ++f)
        acc[f] = __builtin_amdgcn_mfma_f32_16x16x32_bf16(Af[kt], Bf[kt][f], acc[f], 0, 0, 0);
    __builtin_amdgcn_s_setprio(0);

    // every lane holds Y[v][its cols] for all 4 rows; this lane updates row q
    const float yr0 = sel4(acc[0], q), yr1 = sel4(acc[1], q);
    const float yu0 = sel4(acc[2], q), yu1 = sel4(acc[3], q);
    const float g = attn_sT[t * 4 + q];  // 16-lane broadcast

    const float r0 = 1.f / (1.f + __expf(-(fr0 + yr0)));
    const float x0 = fc0 + r0 * (yu0 + ub0);
    const float e0 = __expf(2.f * x0);
    const float h0t = 1.f - 2.f / (e0 + 1.f);
    cm0 += g * (h0t - cm0);

    const float r1 = 1.f / (1.f + __expf(-(fr1 + yr1)));
    const float x1 = fc1 + r1 * (yu1 + ub1);
    const float e1 = __expf(2.f * x1);
    const float h1t = 1.f - 2.f / (e1 + 1.f);
    cm1 += g * (h1t - cm1);

    Cw[q * 136 + w * 16 + l15] = cvtpk(cm0, cm1);  // storage cols (2*l15, 2*l15+1)

    fr0 = nr0; fr1 = nr1; fc0 = nc0; fc1 = nc1;
    __syncthreads();  // single barrier: C writes complete before next Af reads
  }

  // final state in Cbf[0] (t=63 wrote buf 0); 4 rows x 128 dwords
  {
    const int row = tid >> 7, wo = tid & 127;
    ((unsigned int*)Cout)[(n * SS + i0 + row) * 128 + wo] =
        *(const unsigned int*)&Cbf[0][row * 272 + wo * 2];
  }
}

// ---------------------------------------------------------------------------
// Phase D: next_mem = relu([prevM | C | questions] @ nm_w^T + nm_b)
// Tile 64 rows x 32 cols -> 128 blocks (was 64: only 64 CUs engaged).
// (cbf and nmbf's middle K-section share the same K permutation -> invariant)
// ---------------------------------------------------------------------------
__global__ __launch_bounds__(256) void next_mem_gemm(
    const unsigned short* __restrict__ pmbf, const unsigned short* __restrict__ cbf,
    const unsigned short* __restrict__ qbf, const unsigned short* __restrict__ nmbf,
    const float* __restrict__ nmb, float* __restrict__ out) {
  __shared__ unsigned short A[64][40];  // stride 40 bf16 (20 words -> 2-way max)
  const int bi = blockIdx.x;
  const int rb = bi >> 3, cb = bi & 7;
  const int r0 = rb * 64, c0 = cb * 32;
  const int tid = threadIdx.x, w = tid >> 6, l = tid & 63;
  const int l15 = l & 15, q = l >> 4;

  f32x4 acc[2];
  const f32x4 z4 = {0.f, 0.f, 0.f, 0.f};
#pragma unroll
  for (int nf = 0; nf < 2; ++nf) acc[nf] = z4;

  for (int kt = 0; kt < 24; ++kt) {
    const int kg = kt * 32;
    const unsigned short* src =
        kg < 256 ? (pmbf + kg) : (kg < 512 ? (cbf + kg - 256) : (qbf + kg - 512));
    const int kk = (tid & 15) * 2;
#pragma unroll
    for (int ps = 0; ps < 4; ++ps) {
      const int row = ps * 16 + (tid >> 4);
      *(unsigned int*)&A[row][kk] = *(const unsigned int*)(src + (r0 + row) * HH + kk);
    }
    __syncthreads();
    short8 Bfr[2];
#pragma unroll
    for (int nf = 0; nf < 2; ++nf)
      Bfr[nf] = *(const short8*)(nmbf + (c0 + nf * 16 + l15) * 768 + kg + q * 8);
    const short8 Af = *(const short8*)&A[w * 16 + l15][q * 8];
#pragma unroll
    for (int nf = 0; nf < 2; ++nf)
      acc[nf] = __builtin_amdgcn_mfma_f32_16x16x32_bf16(Af, Bfr[nf], acc[nf], 0, 0, 0);
    __syncthreads();
  }
#pragma unroll
  for (int nf = 0; nf < 2; ++nf) {
    const int col = c0 + nf * 16 + l15;
    const float bv = nmb[col];
#pragma unroll
    for (int v = 0; v < 4; ++v) {
      const int grow = r0 + w * 16 + q * 4 + v;
      out[grow * HH + col] = fmaxf(acc[nf][v] + bv, 0.f);
    }
  }
}

// ---------------------------------------------------------------------------
extern "C" void kernel_launch(void* const* d_in, const int* in_sizes, int n_in,
                              void* d_out, int out_size, void* d_ws, size_t ws_size,
                              hipStream_t stream) {
  const float* facts     = (const float*)d_in[0];
  const float* prevM     = (const float*)d_in[1];
  const float* questions = (const float*)d_in[2];
  const int*   doc_len   = (const int*)d_in[3];
  const float* z1w = (const float*)d_in[4];
  const float* z1b = (const float*)d_in[5];
  const float* z2w = (const float*)d_in[6];
  const float* z2b = (const float*)d_in[7];
  const float* Wrw = (const float*)d_in[8];
  const float* Wrb = (const float*)d_in[9];
  const float* Urw = (const float*)d_in[10];
  const float* Urb = (const float*)d_in[11];
  const float* Ww  = (const float*)d_in[12];
  const float* Wb  = (const float*)d_in[13];
  const float* Uw  = (const float*)d_in[14];
  const float* Ub  = (const float*)d_in[15];
  const float* nmw = (const float*)d_in[16];
  const float* nmb = (const float*)d_in[17];

  char* ws = (char*)d_ws;
  unsigned short* z1wbf  = (unsigned short*)(ws + 0);        // 512 KB
  unsigned short* wcatbf = (unsigned short*)(ws + 524288);   // 256 KB
  unsigned short* nmbf   = (unsigned short*)(ws + 786432);   // 384 KB
  unsigned short* pmbf   = (unsigned short*)(ws + 1179648);  // 512 KB
  unsigned short* qbf    = (unsigned short*)(ws + 1703936);  // 512 KB
  float* FWr = (float*)(ws + 2490368);                       // 1 MB
  float* FW  = (float*)(ws + 3538944);                       // 1 MB
  unsigned short* cbf = (unsigned short*)(ws + 4587520);     // 512 KB  (total ~4.9 MB)

  float* out  = (float*)d_out;
  float* attn = out + NB * SS * HH;  // second output region

  prolog_cvt<<<4352, 256, 0, stream>>>(z1w, Urw, Uw, nmw, prevM, questions,
                                       z1wbf, wcatbf, nmbf, pmbf, qbf);
  fact_proj<<<256, 256, 0, stream>>>(facts, Wrw, Wrb, Urb, Ww, Wb, FWr, FW);
  gate_gemm<<<512, 512, 0, stream>>>(facts, prevM, questions, z1wbf, z1b, z2w, z2b,
                                     doc_len, attn);
  gru_scan<<<256, 512, 0, stream>>>(wcatbf, FWr, FW, Ub, attn, cbf);
  next_mem_gemm<<<128, 256, 0, stream>>>(pmbf, cbf, qbf, nmbf, nmb, out);
}